// Round 2
// baseline (1562.466 us; speedup 1.0000x reference)
//
#include <hip/hip_runtime.h>

// Problem constants (match reference)
constexpr int kNodes  = 500000;
constexpr int kEdges  = 600000;
constexpr int kGraphs = 1024;
constexpr int kD      = 128;      // feature dim
constexpr int kAccStride = 256;   // [node_agg(128) | edge_agg(128)] per graph

// ---------------------------------------------------------------------------
// Node aggregation: batch is sorted, so consecutive rows share a graph id.
// Each thread owns one float4 column (sub) of 64 strided rows; it accumulates
// in registers while the graph id is unchanged and flushes via 4 fp32 global
// atomics on segment change. ~3 flushes/thread -> ~4M atomics total (cheap).
// Layout: 256 thr/block = 8 row-lanes x 32 float4-cols; 512 rows/block.
// ---------------------------------------------------------------------------
__global__ __launch_bounds__(256) void node_agg_kernel(
    const float* __restrict__ x, const int* __restrict__ batch,
    float* __restrict__ acc) {
  const int sub   = threadIdx.x & 31;  // float4 column 0..31
  const int rlane = threadIdx.x >> 5;  // 0..7
  const int row0  = blockIdx.x * 512;

  float4 a = make_float4(0.f, 0.f, 0.f, 0.f);
  int cur_g = -1;
  for (int i = rlane; i < 512; i += 8) {
    const int r = row0 + i;
    if (r >= kNodes) break;
    const int g = batch[r];
    if (g != cur_g) {
      if (cur_g >= 0) {
        float* p = acc + (size_t)cur_g * kAccStride + sub * 4;
        unsafeAtomicAdd(p + 0, a.x);
        unsafeAtomicAdd(p + 1, a.y);
        unsafeAtomicAdd(p + 2, a.z);
        unsafeAtomicAdd(p + 3, a.w);
      }
      cur_g = g;
      a = make_float4(0.f, 0.f, 0.f, 0.f);
    }
    const float4 v = reinterpret_cast<const float4*>(x)[(size_t)r * 32 + sub];
    a.x += v.x; a.y += v.y; a.z += v.z; a.w += v.w;
  }
  if (cur_g >= 0) {
    float* p = acc + (size_t)cur_g * kAccStride + sub * 4;
    unsafeAtomicAdd(p + 0, a.x);
    unsafeAtomicAdd(p + 1, a.y);
    unsafeAtomicAdd(p + 2, a.z);
    unsafeAtomicAdd(p + 3, a.w);
  }
}

// ---------------------------------------------------------------------------
// Edge aggregation: edge->graph mapping is random (gather batch[ei0[r]]),
// so no register-run trick applies. Direct fp32 global atomics (native
// global_atomic_add_f32). 77M atomics -- expected bottleneck; optimize next
// round based on rocprof.
// ---------------------------------------------------------------------------
__global__ __launch_bounds__(256) void edge_agg_kernel(
    const float* __restrict__ edge_attr, const int* __restrict__ ei0,
    const int* __restrict__ batch, float* __restrict__ acc) {
  const int sub   = threadIdx.x & 31;
  const int rlane = threadIdx.x >> 5;
  const int row0  = blockIdx.x * 512;

  for (int i = rlane; i < 512; i += 8) {
    const int r = row0 + i;
    if (r >= kEdges) break;
    const int g = batch[ei0[r]];  // broadcast across the 32 lanes of this row
    const float4 v =
        reinterpret_cast<const float4*>(edge_attr)[(size_t)r * 32 + sub];
    float* p = acc + (size_t)g * kAccStride + 128 + sub * 4;
    unsafeAtomicAdd(p + 0, v.x);
    unsafeAtomicAdd(p + 1, v.y);
    unsafeAtomicAdd(p + 2, v.z);
    unsafeAtomicAdd(p + 3, v.w);
  }
}

// ---------------------------------------------------------------------------
// out[g][j] = relu(b[j] + sum_k inp[g][k] * W[j][k]),
// inp[g] = [node_agg(128) | edge_agg(128) | u(128)].
// One block per graph, 128 threads (thread j = output feature). inp row
// staged in LDS (broadcast reads, conflict-free); W row-major read as float4
// (196KB, L2-resident across the 1024 blocks). ~0.1 GFLOP total.
// ---------------------------------------------------------------------------
__global__ __launch_bounds__(128) void fused_out_kernel(
    const float* __restrict__ acc, const float* __restrict__ u,
    const float* __restrict__ W, const float* __restrict__ b,
    float* __restrict__ out) {
  __shared__ float s_in[384];
  const int g = blockIdx.x;
  const int j = threadIdx.x;  // 0..127

  s_in[j]       = acc[(size_t)g * kAccStride + j];
  s_in[128 + j] = acc[(size_t)g * kAccStride + 128 + j];
  s_in[256 + j] = u[(size_t)g * kD + j];
  __syncthreads();

  float sum = b[j];
  const float4* Wr = reinterpret_cast<const float4*>(W + (size_t)j * 384);
  const float4* Sr = reinterpret_cast<const float4*>(s_in);
#pragma unroll 8
  for (int k = 0; k < 96; ++k) {
    const float4 w = Wr[k];
    const float4 s = Sr[k];
    sum = fmaf(w.x, s.x, sum);
    sum = fmaf(w.y, s.y, sum);
    sum = fmaf(w.z, s.z, sum);
    sum = fmaf(w.w, s.w, sum);
  }
  out[(size_t)g * kD + j] = fmaxf(sum, 0.f);
}

// ---------------------------------------------------------------------------
extern "C" void kernel_launch(void* const* d_in, const int* in_sizes, int n_in,
                              void* d_out, int out_size, void* d_ws,
                              size_t ws_size, hipStream_t stream) {
  const float* x         = (const float*)d_in[0];
  const int*   edge_idx  = (const int*)d_in[1];   // [2][kEdges], row-major
  const float* edge_attr = (const float*)d_in[2];
  const float* u         = (const float*)d_in[3];
  const int*   batch     = (const int*)d_in[4];
  const float* W         = (const float*)d_in[5];
  const float* b         = (const float*)d_in[6];
  float*       out       = (float*)d_out;

  float* acc = (float*)d_ws;  // [kGraphs][kAccStride] fp32 accumulators (1 MB)
  hipMemsetAsync(acc, 0, (size_t)kGraphs * kAccStride * sizeof(float), stream);

  node_agg_kernel<<<(kNodes + 511) / 512, 256, 0, stream>>>(x, batch, acc);
  edge_agg_kernel<<<(kEdges + 511) / 512, 256, 0, stream>>>(edge_attr, edge_idx,
                                                            batch, acc);
  fused_out_kernel<<<kGraphs, 128, 0, stream>>>(acc, u, W, b, out);
}

// Round 5
// 666.361 us; speedup vs baseline: 2.3448x; 2.3448x over previous
//
#include <hip/hip_runtime.h>

// Problem constants (match reference)
constexpr int kNodes  = 500000;
constexpr int kEdges  = 600000;
constexpr int kGraphs = 1024;
constexpr int kD      = 128;   // feature dim
constexpr int kNP     = 16;    // bin-privatization groups (cuts same-address atomic hits 16x)
constexpr int kBins   = kGraphs * kNP;                  // 16384
constexpr int kEPB    = 1024;  // edges per hist/scatter block
constexpr int kHistBlocks = (kEdges + kEPB - 1) / kEPB; // 586

// ---------------------------------------------------------------------------
// Workspace layout (bytes). Total ~4.6 MB (proven-safe: 5.86 MB used in r3).
// ---------------------------------------------------------------------------
constexpr size_t kAccNOff  = 0;                          // [2][1024][128] f32 = 1 MB (node partials)
constexpr size_t kAccEOff  = 1u << 20;                   // [2][1024][128] f32 = 1 MB (edge partials)
constexpr size_t kOrderOff = 2u << 20;                   // 600000 i32 (edge ids, graph-grouped)
constexpr size_t kCntOff   = (2u << 20) + 2400000;       // 16384 i32 bins [g][p]
constexpr size_t kOffsOff  = kCntOff + 65536;            // 16384 i32 exclusive scan
constexpr size_t kCursOff  = kOffsOff + 65536;           // 16384 i32 scatter cursors

// ---------------------------------------------------------------------------
// Sort pass 1: histogram into 16x-privatized bins. Bin for edge r is
// (g, p = chunk(r) & 15); all edges of one block share p, so concurrent
// blocks with different p hit disjoint cursor lines -> ~37 same-address hits
// per bin (vs 586 unprivatized; round-3 scatter showed 586 x ~185cy = 45us).
// Fire-and-forget int atomics; ei0 read as int4 (4 edges/thread).
// ---------------------------------------------------------------------------
__global__ __launch_bounds__(256) void hist_kernel(
    const int* __restrict__ ei0, const int* __restrict__ batch,
    int* __restrict__ counts) {
  const int b = blockIdx.x;
  const int base = b * kEPB + threadIdx.x * 4;
  int* cp = counts + (b & (kNP - 1));
  if (base + 3 < kEdges) {
    const int4 e = *reinterpret_cast<const int4*>(ei0 + base);
    atomicAdd(cp + batch[e.x] * kNP, 1);
    atomicAdd(cp + batch[e.y] * kNP, 1);
    atomicAdd(cp + batch[e.z] * kNP, 1);
    atomicAdd(cp + batch[e.w] * kNP, 1);
  } else {
    for (int j = 0; j < 4; ++j) {
      const int r = base + j;
      if (r < kEdges) atomicAdd(cp + batch[ei0[r]] * kNP, 1);
    }
  }
}

// ---------------------------------------------------------------------------
// Sort pass 2: exclusive prefix over 16384 bins, bin order = g*16+p so each
// graph's 16 sub-bins are contiguous. One 1024-thread block: 16 serial values
// per thread + Hillis-Steele across threads. Writes offs (segment starts,
// read by sum_kernel) and curs (mutable scatter cursors).
// ---------------------------------------------------------------------------
__global__ __launch_bounds__(1024) void scan_kernel(
    const int* __restrict__ counts, int* __restrict__ offs,
    int* __restrict__ curs) {
  __shared__ int s[1024];
  const int t = threadIdx.x;
  int v[16];
  int tot = 0;
#pragma unroll
  for (int k = 0; k < 16; ++k) {
    v[k] = counts[t * 16 + k];
    tot += v[k];
  }
  s[t] = tot;
  __syncthreads();
  for (int off = 1; off < 1024; off <<= 1) {
    const int add = (t >= off) ? s[t - off] : 0;
    __syncthreads();
    s[t] += add;
    __syncthreads();
  }
  int run = s[t] - tot;  // exclusive base of this thread's 16 bins
#pragma unroll
  for (int k = 0; k < 16; ++k) {
    offs[t * 16 + k] = run;
    curs[t * 16 + k] = run;
    run += v[k];
  }
}

// ---------------------------------------------------------------------------
// Sort pass 3: scatter edge ids into graph-grouped order via privatized
// cursors. Re-gathers batch[ei0[r]] (batch = 2 MB, L2-resident) instead of
// storing a gid array -- keeps workspace under the proven budget. 4 edges
// per thread -> 4 independent atomic round-trips in flight.
// ---------------------------------------------------------------------------
__global__ __launch_bounds__(256) void scatter_kernel(
    const int* __restrict__ ei0, const int* __restrict__ batch,
    int* __restrict__ curs, int* __restrict__ order) {
  const int b = blockIdx.x;
  const int base = b * kEPB + threadIdx.x * 4;
  int* cp = curs + (b & (kNP - 1));
  if (base + 3 < kEdges) {
    const int4 e = *reinterpret_cast<const int4*>(ei0 + base);
    const int p0 = atomicAdd(cp + batch[e.x] * kNP, 1);
    const int p1 = atomicAdd(cp + batch[e.y] * kNP, 1);
    const int p2 = atomicAdd(cp + batch[e.z] * kNP, 1);
    const int p3 = atomicAdd(cp + batch[e.w] * kNP, 1);
    order[p0] = base;
    order[p1] = base + 1;
    order[p2] = base + 2;
    order[p3] = base + 3;
  } else {
    for (int j = 0; j < 4; ++j) {
      const int r = base + j;
      if (r < kEdges) {
        const int pos = atomicAdd(cp + batch[ei0[r]] * kNP, 1);
        order[pos] = r;
      }
    }
  }
}

// ---------------------------------------------------------------------------
// Fused node+edge aggregation. Round-3 showed both sum kernels at 2.3-2.7
// TB/s with 12-24% occupancy (1 load in flight/thread, serialized kernels).
// Fix: (a) one kernel, blocks [0,2048) = edge halves, [2048,4096) = node
// halves -> independent streams overlap; (b) each graph split across 2
// blocks writing partials (accN/accE[half][g][128]); (c) row loops unrolled
// 4x with 4 independent float4 accumulators -> 4 loads in flight/thread.
// Layout per block: 256 thr = 8 row-lanes x 32 float4-cols.
// ---------------------------------------------------------------------------
__global__ __launch_bounds__(256) void sum_kernel(
    const float* __restrict__ x, const int* __restrict__ batch,
    const float* __restrict__ edge_attr, const int* __restrict__ order,
    const int* __restrict__ offs, float* __restrict__ accN,
    float* __restrict__ accE) {
  __shared__ int s_b[2];
  __shared__ int s_idx[1024];
  __shared__ float s_red[8][128];
  const int tid = threadIdx.x;
  const int sub = tid & 31, rlane = tid >> 5;

  float4 a0 = make_float4(0.f, 0.f, 0.f, 0.f);
  float4 a1 = a0, a2 = a0, a3 = a0;
  float* dst;

  if (blockIdx.x < 2 * kGraphs) {
    // ---- edge half-block: gather graph g's edge rows via order[] ----
    const int g = blockIdx.x >> 1, h = blockIdx.x & 1;
    if (tid == 0) {
      const int s = offs[g * kNP];
      const int e = (g == kGraphs - 1) ? kEdges : offs[(g + 1) * kNP];
      const int mid = (s + e) >> 1;
      s_b[0] = h ? mid : s;
      s_b[1] = h ? e : mid;
    }
    __syncthreads();
    const int s = s_b[0], e = s_b[1];
    const float4* rows = reinterpret_cast<const float4*>(edge_attr);
    for (int t0 = s; t0 < e; t0 += 1024) {
      const int n = min(1024, e - t0);
      __syncthreads();  // protect s_idx from previous tile's readers
      for (int i = tid; i < n; i += 256) s_idx[i] = order[t0 + i];
      __syncthreads();
      int i = rlane;
      for (; i + 24 < n; i += 32) {
        const int i0 = s_idx[i], i1 = s_idx[i + 8];
        const int i2 = s_idx[i + 16], i3 = s_idx[i + 24];
        const float4 v0 = rows[(size_t)i0 * 32 + sub];
        const float4 v1 = rows[(size_t)i1 * 32 + sub];
        const float4 v2 = rows[(size_t)i2 * 32 + sub];
        const float4 v3 = rows[(size_t)i3 * 32 + sub];
        a0.x += v0.x; a0.y += v0.y; a0.z += v0.z; a0.w += v0.w;
        a1.x += v1.x; a1.y += v1.y; a1.z += v1.z; a1.w += v1.w;
        a2.x += v2.x; a2.y += v2.y; a2.z += v2.z; a2.w += v2.w;
        a3.x += v3.x; a3.y += v3.y; a3.z += v3.z; a3.w += v3.w;
      }
      for (; i < n; i += 8) {
        const float4 v = rows[(size_t)s_idx[i] * 32 + sub];
        a0.x += v.x; a0.y += v.y; a0.z += v.z; a0.w += v.w;
      }
    }
    dst = accE + ((size_t)h * kGraphs + g) * kD;
  } else {
    // ---- node half-block: batch sorted -> contiguous row range ----
    const int bb = blockIdx.x - 2 * kGraphs;
    const int g = bb >> 1, h = bb & 1;
    if (tid < 2) {
      const int target = g + tid;
      int lo = 0, hi = kNodes;
      while (lo < hi) {
        const int mid = (lo + hi) >> 1;
        if (batch[mid] < target) lo = mid + 1; else hi = mid;
      }
      s_b[tid] = lo;
    }
    __syncthreads();
    const int s = s_b[0], e = s_b[1];
    const int mid = (s + e) >> 1;
    const int s0 = h ? mid : s, e0 = h ? e : mid;
    const float4* rows = reinterpret_cast<const float4*>(x);
    int r = s0 + rlane;
    for (; r + 24 < e0; r += 32) {
      const float4 v0 = rows[(size_t)r * 32 + sub];
      const float4 v1 = rows[(size_t)(r + 8) * 32 + sub];
      const float4 v2 = rows[(size_t)(r + 16) * 32 + sub];
      const float4 v3 = rows[(size_t)(r + 24) * 32 + sub];
      a0.x += v0.x; a0.y += v0.y; a0.z += v0.z; a0.w += v0.w;
      a1.x += v1.x; a1.y += v1.y; a1.z += v1.z; a1.w += v1.w;
      a2.x += v2.x; a2.y += v2.y; a2.z += v2.z; a2.w += v2.w;
      a3.x += v3.x; a3.y += v3.y; a3.z += v3.z; a3.w += v3.w;
    }
    for (; r < e0; r += 8) {
      const float4 v = rows[(size_t)r * 32 + sub];
      a0.x += v.x; a0.y += v.y; a0.z += v.z; a0.w += v.w;
    }
    dst = accN + ((size_t)h * kGraphs + g) * kD;
  }

  // ---- shared epilogue: combine 4 accumulators, LDS tree-reduce, store ----
  a0.x += a1.x + a2.x + a3.x;
  a0.y += a1.y + a2.y + a3.y;
  a0.z += a1.z + a2.z + a3.z;
  a0.w += a1.w + a2.w + a3.w;
  s_red[rlane][sub * 4 + 0] = a0.x;
  s_red[rlane][sub * 4 + 1] = a0.y;
  s_red[rlane][sub * 4 + 2] = a0.z;
  s_red[rlane][sub * 4 + 3] = a0.w;
  __syncthreads();
  if (tid < kD) {
    float sm = 0.f;
#pragma unroll
    for (int k = 0; k < 8; ++k) sm += s_red[k][tid];
    dst[tid] = sm;
  }
}

// ---------------------------------------------------------------------------
// out[g][j] = relu(b[j] + sum_k inp[g][k] * W[j][k]),
// inp[g] = [accN0+accN1 | accE0+accE1 | u]. One block per graph.
// ---------------------------------------------------------------------------
__global__ __launch_bounds__(128) void fused_out_kernel(
    const float* __restrict__ accN, const float* __restrict__ accE,
    const float* __restrict__ u, const float* __restrict__ W,
    const float* __restrict__ b, float* __restrict__ out) {
  __shared__ float s_in[384];
  const int g = blockIdx.x;
  const int j = threadIdx.x;  // 0..127
  constexpr size_t kHalf = (size_t)kGraphs * kD;  // 131072

  s_in[j]       = accN[(size_t)g * kD + j] + accN[kHalf + (size_t)g * kD + j];
  s_in[128 + j] = accE[(size_t)g * kD + j] + accE[kHalf + (size_t)g * kD + j];
  s_in[256 + j] = u[(size_t)g * kD + j];
  __syncthreads();

  float sum = b[j];
  const float4* Wr = reinterpret_cast<const float4*>(W + (size_t)j * 384);
  const float4* Sr = reinterpret_cast<const float4*>(s_in);
#pragma unroll 8
  for (int k = 0; k < 96; ++k) {
    const float4 w = Wr[k];
    const float4 s = Sr[k];
    sum = fmaf(w.x, s.x, sum);
    sum = fmaf(w.y, s.y, sum);
    sum = fmaf(w.z, s.z, sum);
    sum = fmaf(w.w, s.w, sum);
  }
  out[(size_t)g * kD + j] = fmaxf(sum, 0.f);
}

// ---------------------------------------------------------------------------
extern "C" void kernel_launch(void* const* d_in, const int* in_sizes, int n_in,
                              void* d_out, int out_size, void* d_ws,
                              size_t ws_size, hipStream_t stream) {
  const float* x         = (const float*)d_in[0];
  const int*   edge_idx  = (const int*)d_in[1];   // [2][kEdges], row-major
  const float* edge_attr = (const float*)d_in[2];
  const float* u         = (const float*)d_in[3];
  const int*   batch     = (const int*)d_in[4];
  const float* W         = (const float*)d_in[5];
  const float* b         = (const float*)d_in[6];
  float*       out       = (float*)d_out;

  char* ws = (char*)d_ws;
  float* accN   = (float*)(ws + kAccNOff);
  float* accE   = (float*)(ws + kAccEOff);
  int*   order  = (int*)(ws + kOrderOff);
  int*   counts = (int*)(ws + kCntOff);
  int*   offs   = (int*)(ws + kOffsOff);
  int*   curs   = (int*)(ws + kCursOff);

  // Only the bin histogram needs zero-init; all else is fully overwritten.
  hipMemsetAsync(counts, 0, kBins * sizeof(int), stream);

  hist_kernel<<<kHistBlocks, 256, 0, stream>>>(edge_idx, batch, counts);
  scan_kernel<<<1, 1024, 0, stream>>>(counts, offs, curs);
  scatter_kernel<<<kHistBlocks, 256, 0, stream>>>(edge_idx, batch, curs, order);
  sum_kernel<<<4 * kGraphs, 256, 0, stream>>>(x, batch, edge_attr, order, offs,
                                              accN, accE);
  fused_out_kernel<<<kGraphs, 128, 0, stream>>>(accN, accE, u, W, b, out);
}

// Round 7
// 665.420 us; speedup vs baseline: 2.3481x; 1.0014x over previous
//
#include <hip/hip_runtime.h>

// Problem constants (match reference)
constexpr int kNodes  = 500000;
constexpr int kEdges  = 600000;
constexpr int kGraphs = 1024;
constexpr int kD      = 128;   // feature dim
constexpr int kNP     = 16;    // bin-privatization groups for the counting sort
constexpr int kBins   = kGraphs * kNP;                  // 16384
constexpr int kEPB    = 1024;  // edges per hist/scatter block
constexpr int kHistBlocks = (kEdges + kEPB - 1) / kEPB; // 586

// ---------------------------------------------------------------------------
// Workspace layout (bytes). Total ~4.6 MB -- exact layout verified in round 5.
// ---------------------------------------------------------------------------
constexpr size_t kAccNOff  = 0;                          // [2][1024][128] f32 (node partials)
constexpr size_t kAccEOff  = 1u << 20;                   // [2][1024][128] f32 (edge partials)
constexpr size_t kOrderOff = 2u << 20;                   // 600000 i32 (graph-grouped edge ids)
constexpr size_t kCntOff   = (2u << 20) + 2400000;       // 16384 i32 bins [g][p]
constexpr size_t kOffsOff  = kCntOff + 65536;            // 16384 i32 exclusive scan
constexpr size_t kCursOff  = kOffsOff + 65536;           // 16384 i32 scatter cursors

// ---------------------------------------------------------------------------
// Sort pass 1 (verified r5): histogram into 16x-privatized bins.
// ---------------------------------------------------------------------------
__global__ __launch_bounds__(256) void hist_kernel(
    const int* __restrict__ ei0, const int* __restrict__ batch,
    int* __restrict__ counts) {
  const int b = blockIdx.x;
  const int base = b * kEPB + threadIdx.x * 4;
  int* cp = counts + (b & (kNP - 1));
  if (base + 3 < kEdges) {
    const int4 e = *reinterpret_cast<const int4*>(ei0 + base);
    atomicAdd(cp + batch[e.x] * kNP, 1);
    atomicAdd(cp + batch[e.y] * kNP, 1);
    atomicAdd(cp + batch[e.z] * kNP, 1);
    atomicAdd(cp + batch[e.w] * kNP, 1);
  } else {
    for (int j = 0; j < 4; ++j) {
      const int r = base + j;
      if (r < kEdges) atomicAdd(cp + batch[ei0[r]] * kNP, 1);
    }
  }
}

// ---------------------------------------------------------------------------
// Sort pass 2 (verified r5): exclusive prefix over 16384 bins, order g*16+p.
// ---------------------------------------------------------------------------
__global__ __launch_bounds__(1024) void scan_kernel(
    const int* __restrict__ counts, int* __restrict__ offs,
    int* __restrict__ curs) {
  __shared__ int s[1024];
  const int t = threadIdx.x;
  int v[16];
  int tot = 0;
#pragma unroll
  for (int k = 0; k < 16; ++k) {
    v[k] = counts[t * 16 + k];
    tot += v[k];
  }
  s[t] = tot;
  __syncthreads();
  for (int off = 1; off < 1024; off <<= 1) {
    const int add = (t >= off) ? s[t - off] : 0;
    __syncthreads();
    s[t] += add;
    __syncthreads();
  }
  int run = s[t] - tot;  // exclusive base of this thread's 16 bins
#pragma unroll
  for (int k = 0; k < 16; ++k) {
    offs[t * 16 + k] = run;
    curs[t * 16 + k] = run;
    run += v[k];
  }
}

// ---------------------------------------------------------------------------
// Sort pass 3 (verified r5): scatter edge ids via privatized cursors.
// ---------------------------------------------------------------------------
__global__ __launch_bounds__(256) void scatter_kernel(
    const int* __restrict__ ei0, const int* __restrict__ batch,
    int* __restrict__ curs, int* __restrict__ order) {
  const int b = blockIdx.x;
  const int base = b * kEPB + threadIdx.x * 4;
  int* cp = curs + (b & (kNP - 1));
  if (base + 3 < kEdges) {
    const int4 e = *reinterpret_cast<const int4*>(ei0 + base);
    const int p0 = atomicAdd(cp + batch[e.x] * kNP, 1);
    const int p1 = atomicAdd(cp + batch[e.y] * kNP, 1);
    const int p2 = atomicAdd(cp + batch[e.z] * kNP, 1);
    const int p3 = atomicAdd(cp + batch[e.w] * kNP, 1);
    order[p0] = base;
    order[p1] = base + 1;
    order[p2] = base + 2;
    order[p3] = base + 3;
  } else {
    for (int j = 0; j < 4; ++j) {
      const int r = base + j;
      if (r < kEdges) {
        const int pos = atomicAdd(cp + batch[ei0[r]] * kNP, 1);
        order[pos] = r;
      }
    }
  }
}

// ---------------------------------------------------------------------------
// Node aggregation: batch sorted -> block (g,h) sums half of graph g's
// contiguous row range. 4x unrolled, 4 independent float4 accumulators
// (4 loads in flight), LDS tree-reduce, non-atomic partial store. Grid 2048.
// ---------------------------------------------------------------------------
__global__ __launch_bounds__(256) void node_sum_kernel(
    const float* __restrict__ x, const int* __restrict__ batch,
    float* __restrict__ accN) {
  __shared__ int s_b[2];
  __shared__ float s_red[8][128];
  const int tid = threadIdx.x;
  const int sub = tid & 31, rlane = tid >> 5;
  const int g = blockIdx.x >> 1, h = blockIdx.x & 1;

  if (tid < 2) {
    const int target = g + tid;
    int lo = 0, hi = kNodes;
    while (lo < hi) {
      const int mid = (lo + hi) >> 1;
      if (batch[mid] < target) lo = mid + 1; else hi = mid;
    }
    s_b[tid] = lo;
  }
  __syncthreads();
  const int s = s_b[0], e = s_b[1];
  const int mid = (s + e) >> 1;
  const int s0 = h ? mid : s, e0 = h ? e : mid;

  float4 a0 = make_float4(0.f, 0.f, 0.f, 0.f);
  float4 a1 = a0, a2 = a0, a3 = a0;
  const float4* rows = reinterpret_cast<const float4*>(x);
  int r = s0 + rlane;
  for (; r + 24 < e0; r += 32) {
    const float4 v0 = rows[(size_t)r * 32 + sub];
    const float4 v1 = rows[(size_t)(r + 8) * 32 + sub];
    const float4 v2 = rows[(size_t)(r + 16) * 32 + sub];
    const float4 v3 = rows[(size_t)(r + 24) * 32 + sub];
    a0.x += v0.x; a0.y += v0.y; a0.z += v0.z; a0.w += v0.w;
    a1.x += v1.x; a1.y += v1.y; a1.z += v1.z; a1.w += v1.w;
    a2.x += v2.x; a2.y += v2.y; a2.z += v2.z; a2.w += v2.w;
    a3.x += v3.x; a3.y += v3.y; a3.z += v3.z; a3.w += v3.w;
  }
  for (; r < e0; r += 8) {
    const float4 v = rows[(size_t)r * 32 + sub];
    a0.x += v.x; a0.y += v.y; a0.z += v.z; a0.w += v.w;
  }

  a0.x += a1.x + a2.x + a3.x;
  a0.y += a1.y + a2.y + a3.y;
  a0.z += a1.z + a2.z + a3.z;
  a0.w += a1.w + a2.w + a3.w;
  s_red[rlane][sub * 4 + 0] = a0.x;
  s_red[rlane][sub * 4 + 1] = a0.y;
  s_red[rlane][sub * 4 + 2] = a0.z;
  s_red[rlane][sub * 4 + 3] = a0.w;
  __syncthreads();
  if (tid < kD) {
    float sm = 0.f;
#pragma unroll
    for (int k = 0; k < 8; ++k) sm += s_red[k][tid];
    accN[((size_t)h * kGraphs + g) * kD + tid] = sm;
  }
}

// ---------------------------------------------------------------------------
// Edge aggregation: block (g,h) gathers half of graph g's edge rows via
// order[]. Index tile staged in LDS; 4x unrolled gather (4 x 512B rows in
// flight); LDS tree-reduce; partial store. Grid 2048.
// ---------------------------------------------------------------------------
__global__ __launch_bounds__(256) void edge_sum_kernel(
    const float* __restrict__ edge_attr, const int* __restrict__ order,
    const int* __restrict__ offs, float* __restrict__ accE) {
  __shared__ int s_b[2];
  __shared__ int s_idx[1024];
  __shared__ float s_red[8][128];
  const int tid = threadIdx.x;
  const int sub = tid & 31, rlane = tid >> 5;
  const int g = blockIdx.x >> 1, h = blockIdx.x & 1;

  if (tid == 0) {
    const int s = offs[g * kNP];
    const int e = (g == kGraphs - 1) ? kEdges : offs[(g + 1) * kNP];
    const int mid = (s + e) >> 1;
    s_b[0] = h ? mid : s;
    s_b[1] = h ? e : mid;
  }
  __syncthreads();
  const int s = s_b[0], e = s_b[1];

  float4 a0 = make_float4(0.f, 0.f, 0.f, 0.f);
  float4 a1 = a0, a2 = a0, a3 = a0;
  const float4* rows = reinterpret_cast<const float4*>(edge_attr);
  for (int t0 = s; t0 < e; t0 += 1024) {
    const int n = min(1024, e - t0);
    __syncthreads();  // protect s_idx from previous tile's readers
    for (int i = tid; i < n; i += 256) s_idx[i] = order[t0 + i];
    __syncthreads();
    int i = rlane;
    for (; i + 24 < n; i += 32) {
      const int i0 = s_idx[i], i1 = s_idx[i + 8];
      const int i2 = s_idx[i + 16], i3 = s_idx[i + 24];
      const float4 v0 = rows[(size_t)i0 * 32 + sub];
      const float4 v1 = rows[(size_t)i1 * 32 + sub];
      const float4 v2 = rows[(size_t)i2 * 32 + sub];
      const float4 v3 = rows[(size_t)i3 * 32 + sub];
      a0.x += v0.x; a0.y += v0.y; a0.z += v0.z; a0.w += v0.w;
      a1.x += v1.x; a1.y += v1.y; a1.z += v1.z; a1.w += v1.w;
      a2.x += v2.x; a2.y += v2.y; a2.z += v2.z; a2.w += v2.w;
      a3.x += v3.x; a3.y += v3.y; a3.z += v3.z; a3.w += v3.w;
    }
    for (; i < n; i += 8) {
      const float4 v = rows[(size_t)s_idx[i] * 32 + sub];
      a0.x += v.x; a0.y += v.y; a0.z += v.z; a0.w += v.w;
    }
  }

  a0.x += a1.x + a2.x + a3.x;
  a0.y += a1.y + a2.y + a3.y;
  a0.z += a1.z + a2.z + a3.z;
  a0.w += a1.w + a2.w + a3.w;
  s_red[rlane][sub * 4 + 0] = a0.x;
  s_red[rlane][sub * 4 + 1] = a0.y;
  s_red[rlane][sub * 4 + 2] = a0.z;
  s_red[rlane][sub * 4 + 3] = a0.w;
  __syncthreads();
  if (tid < kD) {
    float sm = 0.f;
#pragma unroll
    for (int k = 0; k < 8; ++k) sm += s_red[k][tid];
    accE[((size_t)h * kGraphs + g) * kD + tid] = sm;
  }
}

// ---------------------------------------------------------------------------
// out[g][j] = relu(b[j] + sum_k inp[g][k] * W[j][k]),
// inp[g] = [accN0+accN1 | accE0+accE1 | u]. One block per graph (verified r5).
// ---------------------------------------------------------------------------
__global__ __launch_bounds__(128) void fused_out_kernel(
    const float* __restrict__ accN, const float* __restrict__ accE,
    const float* __restrict__ u, const float* __restrict__ W,
    const float* __restrict__ b, float* __restrict__ out) {
  __shared__ float s_in[384];
  const int g = blockIdx.x;
  const int j = threadIdx.x;  // 0..127
  constexpr size_t kHalf = (size_t)kGraphs * kD;  // 131072

  s_in[j]       = accN[(size_t)g * kD + j] + accN[kHalf + (size_t)g * kD + j];
  s_in[128 + j] = accE[(size_t)g * kD + j] + accE[kHalf + (size_t)g * kD + j];
  s_in[256 + j] = u[(size_t)g * kD + j];
  __syncthreads();

  float sum = b[j];
  const float4* Wr = reinterpret_cast<const float4*>(W + (size_t)j * 384);
  const float4* Sr = reinterpret_cast<const float4*>(s_in);
#pragma unroll 8
  for (int k = 0; k < 96; ++k) {
    const float4 w = Wr[k];
    const float4 s = Sr[k];
    sum = fmaf(w.x, s.x, sum);
    sum = fmaf(w.y, s.y, sum);
    sum = fmaf(w.z, s.z, sum);
    sum = fmaf(w.w, s.w, sum);
  }
  out[(size_t)g * kD + j] = fmaxf(sum, 0.f);
}

// ---------------------------------------------------------------------------
extern "C" void kernel_launch(void* const* d_in, const int* in_sizes, int n_in,
                              void* d_out, int out_size, void* d_ws,
                              size_t ws_size, hipStream_t stream) {
  const float* x         = (const float*)d_in[0];
  const int*   edge_idx  = (const int*)d_in[1];   // [2][kEdges], row-major
  const float* edge_attr = (const float*)d_in[2];
  const float* u         = (const float*)d_in[3];
  const int*   batch     = (const int*)d_in[4];
  const float* W         = (const float*)d_in[5];
  const float* b         = (const float*)d_in[6];
  float*       out       = (float*)d_out;

  char* ws = (char*)d_ws;
  float* accN   = (float*)(ws + kAccNOff);
  float* accE   = (float*)(ws + kAccEOff);
  int*   order  = (int*)(ws + kOrderOff);
  int*   counts = (int*)(ws + kCntOff);
  int*   offs   = (int*)(ws + kOffsOff);
  int*   curs   = (int*)(ws + kCursOff);

  // Only the bin histogram needs zero-init; all else is fully overwritten.
  hipMemsetAsync(counts, 0, kBins * sizeof(int), stream);

  hist_kernel<<<kHistBlocks, 256, 0, stream>>>(edge_idx, batch, counts);
  scan_kernel<<<1, 1024, 0, stream>>>(counts, offs, curs);
  scatter_kernel<<<kHistBlocks, 256, 0, stream>>>(edge_idx, batch, curs, order);
  node_sum_kernel<<<2 * kGraphs, 256, 0, stream>>>(x, batch, accN);
  edge_sum_kernel<<<2 * kGraphs, 256, 0, stream>>>(edge_attr, order, offs,
                                                   accE);
  fused_out_kernel<<<kGraphs, 128, 0, stream>>>(accN, accE, u, W, b, out);
}